// Round 3
// baseline (199.539 us; speedup 1.0000x reference)
//
#include <hip/hip_runtime.h>

// SubjectConditionalLinear: y[b,n,o] = sum_h x[b,n,h] * W[sid[b],o,h] + bias[sid[b],o]
// x: [32,512,1024] f32, subject_id: [32] i32, weight: [8,1024,1024] f32, bias: [8,1024] f32
// out: [32,512,1024] f32
//
// R7: fuse x's f32->bf16 into the GEMM. A is staged as RAW f32 via
// global_load_lds (BK=32) and converted to bf16 at fragment-read time
// (ds_read_b128 x2 + 4 cvt_pk per frag). W keeps a small cvt pass (48MB).
// Kills the 96MB x round-trip (~15us of the cvt kernel).
//
// Pipeline: triple-buffered LDS (A f32 3x32K + B bf16 3x16K = 144KiB),
// 2 phases per K-tile(32). Ledger (6 gloads/wave/K-tile, all at P0-tail):
//   P0(kt)-tail: stage[kt+2] x6; VMW(6) retires stage[kt+1]; read afH(kt).
//   P1(kt)-tail: read afL(kt+1), bf(kt+1)  [safe: VMW(6)+BAR precede].
// Every LDS overwrite lands >=2 barriers after its readers. vmcnt never
// drains to 0 except the kt=30 tail.

constexpr int S_DIM = 8;
constexpr int O_DIM = 1024;
constexpr int H_DIM = 1024;
constexpr int B_DIM = 32;
constexpr int N_DIM = 512;

constexpr int BM = 256;
constexpr int BN = 256;
constexpr int BK = 32;
constexpr int NKT = H_DIM / BK;  // 32 K-tiles

typedef short bf16x8 __attribute__((ext_vector_type(8)));
typedef float f32x4 __attribute__((ext_vector_type(4)));
typedef float f32x2 __attribute__((ext_vector_type(2)));
typedef __bf16 bf16x2 __attribute__((ext_vector_type(2)));
typedef unsigned int u32x4 __attribute__((ext_vector_type(4)));

__device__ __forceinline__ unsigned int cvt_pk_bf16(float a, float b) {
  f32x2 v;
  v[0] = a;
  v[1] = b;
  bf16x2 r = __builtin_convertvector(v, bf16x2);  // v_cvt_pk_bf16_f32
  return __builtin_bit_cast(unsigned int, r);
}

__device__ __forceinline__ void gload_lds16(const void* g, void* l) {
  __builtin_amdgcn_global_load_lds(
      (const __attribute__((address_space(1))) unsigned int*)g,
      (__attribute__((address_space(3))) unsigned int*)l, 16, 0, 0);
}

// ---------- Phase 1: fp32 -> bf16 convert, WEIGHTS ONLY (48 MB) ------------
__global__ __launch_bounds__(256) void cvt_w(const float* __restrict__ w,
                                             unsigned short* __restrict__ wb) {
  const long long e0 = (long long)blockIdx.x * 4096 + threadIdx.x * 4;
#pragma unroll
  for (int c = 0; c < 4; ++c) {
    const f32x4 v = __builtin_nontemporal_load((const f32x4*)(w + e0 + c * 1024));
    uint2 u;
    u.x = cvt_pk_bf16(v[0], v[1]);
    u.y = cvt_pk_bf16(v[2], v[3]);
    *(uint2*)(wb + e0 + c * 1024) = u;
  }
}

// ---------- Phase 2: fused f32-A bf16-B MFMA GEMM --------------------------
#define BAR() __builtin_amdgcn_s_barrier()
#define SB0() __builtin_amdgcn_sched_barrier(0)
#define VMW(N) asm volatile("s_waitcnt vmcnt(" #N ")" ::: "memory")
#define LGKM0()                                            \
  do {                                                     \
    asm volatile("s_waitcnt lgkmcnt(0)" ::: "memory");     \
    __builtin_amdgcn_sched_barrier(0);                     \
  } while (0)

// A-fragment quad: f32 LDS -> bf16 regs. Row ar, logical chunks 2lq,2lq+1
// swizzled by ^(ar&7) (= lcol&7, precomputed in pA0/pA1).
#define LDAF(DST, ABUF, MB)                                              \
  do {                                                                   \
    _Pragma("unroll") for (int m_ = 0; m_ < 4; ++m_) {                   \
      const int ar_ = wr * 128 + ((MB) + m_) * 16 + lcol;                \
      const float* ap_ = (ABUF) + ar_ * 32;                              \
      const f32x4 lo_ = *(const f32x4*)(ap_ + pA0);                      \
      const f32x4 hi_ = *(const f32x4*)(ap_ + pA1);                      \
      u32x4 t_;                                                          \
      t_[0] = cvt_pk_bf16(lo_[0], lo_[1]);                               \
      t_[1] = cvt_pk_bf16(lo_[2], lo_[3]);                               \
      t_[2] = cvt_pk_bf16(hi_[0], hi_[1]);                               \
      t_[3] = cvt_pk_bf16(hi_[2], hi_[3]);                               \
      DST[m_] = __builtin_bit_cast(bf16x8, t_);                          \
    }                                                                    \
  } while (0)

// B-fragment quad: bf16 LDS. Row br, chunk lq ^ (br&3) ^ ((br>>2)&3)
// (lane-constant, precomputed pB).
#define LDBF(DST, BBUF)                                                  \
  do {                                                                   \
    _Pragma("unroll") for (int n_ = 0; n_ < 4; ++n_) {                   \
      const int br_ = wc * 64 + n_ * 16 + lcol;                          \
      DST[n_] = *(const bf16x8*)((BBUF) + br_ * 32 + pB);                \
    }                                                                    \
  } while (0)

// One half-quadrant x K=32: 4m x 4n = 16 MFMA.
#define MMQ(AF, MB)                                                      \
  do {                                                                   \
    _Pragma("unroll") for (int m_ = 0; m_ < 4; ++m_)                     \
    _Pragma("unroll") for (int n_ = 0; n_ < 4; ++n_)                     \
      acc[(MB) + m_][n_] = __builtin_amdgcn_mfma_f32_16x16x32_bf16(      \
          AF[m_], bf[n_], acc[(MB) + m_][n_], 0, 0, 0);                  \
  } while (0)

// A unit I (8 rows x 128B f32), B unit J (16 rows x 64B bf16) of K-tile KT.
#define STAGE_AU(I, DSTA, KT)                                            \
  gload_lds16(agA + (size_t)(I) * 8 * H_DIM + (size_t)(KT) * 32,         \
              (DSTA) + (wid * 32 + (I) * 8) * 32)
#define STAGE_BU(J, DSTB, KT)                                            \
  gload_lds16(bgB + (size_t)(J) * 16 * H_DIM + (size_t)(KT) * 32,        \
              (DSTB) + (wid * 32 + (J) * 16) * 32)
#define STAGE6(AS, BS, KT)                                               \
  do {                                                                   \
    STAGE_AU(0, AS, KT);                                                 \
    STAGE_AU(1, AS, KT);                                                 \
    STAGE_AU(2, AS, KT);                                                 \
    STAGE_AU(3, AS, KT);                                                 \
    STAGE_BU(0, BS, KT);                                                 \
    STAGE_BU(1, BS, KT);                                                 \
  } while (0)

// One K-tile, 2 phases. AC/BC = current buf, AN/BN = next, AS/BS = stage dst.
#define KTILE(KT, AC, BC, AN, BN, AS, BS)                                \
  do {                                                                   \
    /* P0: mi 0-3 (uses afL(KT), bf(KT) read in prev P1-tail) */         \
    LGKM0();                                                             \
    __builtin_amdgcn_s_setprio(1);                                       \
    MMQ(afL, 0);                                                         \
    __builtin_amdgcn_s_setprio(0);                                       \
    if ((KT) + 2 < NKT) {                                                \
      STAGE6(AS, BS, (KT) + 2);                                          \
      VMW(6); /* retire stage[KT+1] (issued 2 phases ago) */             \
    } else if ((KT) + 1 < NKT) {                                         \
      VMW(0); /* tail: retire stage[KT+1], nothing newer in flight */    \
    }                                                                    \
    LDAF(afH, AC, 4);                                                    \
    SB0();                                                               \
    BAR();                                                               \
    /* P1: mi 4-7 */                                                     \
    LGKM0();                                                             \
    __builtin_amdgcn_s_setprio(1);                                       \
    MMQ(afH, 4);                                                         \
    __builtin_amdgcn_s_setprio(0);                                       \
    if ((KT) + 1 < NKT) {                                                \
      LDAF(afL, AN, 0); /* safe: VMW(6)+BAR at P0 cover buf(KT+1) */     \
      LDBF(bf, BN);                                                      \
    }                                                                    \
    SB0();                                                               \
    BAR();                                                               \
  } while (0)

__global__ __launch_bounds__(512, 2) void scl_gemm(
    const float* __restrict__ xg, const int* __restrict__ subject_id,
    const unsigned short* __restrict__ wb, const float* __restrict__ bias,
    float* __restrict__ out) {
  __shared__ __align__(16) float Afs[3][BM * 32];           // 3 x 32 KiB
  __shared__ __align__(16) unsigned short Bbs[3][BN * 32];  // 3 x 16 KiB

  const int tid = threadIdx.x;
  const int lane = tid & 63;
  const int wid = tid >> 6;   // 0..7
  const int wr = wid >> 2;    // 0..1  (M half)
  const int wc = wid & 3;     // 0..3  (N quarter)
  const int lcol = lane & 15;
  const int lq = lane >> 4;   // 0..3

  // Lane-constant swizzled fragment offsets.
  const int pA0 = (((2 * lq) ^ (lcol & 7)) << 2);      // floats
  const int pA1 = (((2 * lq + 1) ^ (lcol & 7)) << 2);  // floats
  const int pB = ((lq ^ (lcol & 3) ^ ((lcol >> 2) & 3)) << 3);  // shorts

  // XCD-grouped bijective block map: xcd = bid&7 owns batches 4*xcd..4*xcd+3.
  const int bid = blockIdx.x;
  const int b = (bid & 7) * 4 + ((bid >> 3) & 3);
  const int t = bid >> 5;          // 0..7
  const int n0 = (t & 1) * BM;
  const int o0 = (t >> 1) * BN;
  const int sid = subject_id[b];

  // Staging global bases (swizzle applied on the global side).
  // A (f32): lane L -> row rl=L>>3, phys chunk L&7, logical chunk (L&7)^rl.
  const int rlA = lane >> 3;
  const int skcA = ((lane & 7) ^ rlA) << 2;  // floats
  const float* agA =
      xg + (size_t)(b * N_DIM + n0 + wid * 32 + rlA) * H_DIM + skcA;
  // B (bf16): lane L -> row rlb=L>>2, phys chunk L&3,
  // logical chunk (L&3) ^ (rlb&3) ^ ((rlb>>2)&3).
  const int skcB =
      (((lane & 3) ^ ((lane >> 2) & 3) ^ ((lane >> 4) & 3))) << 3;  // shorts
  const unsigned short* bgB =
      wb + (size_t)(sid * O_DIM + o0 + wid * 32 + (lane >> 2)) * H_DIM + skcB;

  float* const Af0 = &Afs[0][0];
  float* const Af1 = &Afs[1][0];
  float* const Af2 = &Afs[2][0];
  unsigned short* const Bb0 = &Bbs[0][0];
  unsigned short* const Bb1 = &Bbs[1][0];
  unsigned short* const Bb2 = &Bbs[2][0];

  f32x4 acc[8][4];
#pragma unroll
  for (int mi = 0; mi < 8; ++mi)
#pragma unroll
    for (int ni = 0; ni < 4; ++ni) {
      f32x4 z = {0.f, 0.f, 0.f, 0.f};
      acc[mi][ni] = z;
    }

  bf16x8 afL[4];  // mi 0-3 of current kt
  bf16x8 afH[4];  // mi 4-7 of current kt
  bf16x8 bf[4];   // ni 0-3 of current kt

  // Prologue: stage[0], stage[1]; retire stage[0]; first fragment reads.
  STAGE6(Af0, Bb0, 0);
  STAGE6(Af1, Bb1, 1);
  VMW(6);  // 12 outstanding -> retire stage[0]
  BAR();
  LDAF(afL, Af0, 0);
  LDBF(bf, Bb0);
  SB0();

#pragma unroll 1
  for (int kt0 = 0; kt0 < 30; kt0 += 3) {
    KTILE(kt0,     Af0, Bb0, Af1, Bb1, Af2, Bb2);
    KTILE(kt0 + 1, Af1, Bb1, Af2, Bb2, Af0, Bb0);
    KTILE(kt0 + 2, Af2, Bb2, Af0, Bb0, Af1, Bb1);
  }
  KTILE(30, Af0, Bb0, Af1, Bb1, Af2, Bb2);
  KTILE(31, Af1, Bb1, Af2, Bb2, Af0, Bb0);

  // Epilogue: C/D layout col = lane&15, row = (lane>>4)*4 + reg.
  float bv[4];
#pragma unroll
  for (int ni = 0; ni < 4; ++ni)
    bv[ni] = bias[sid * O_DIM + o0 + wc * 64 + ni * 16 + lcol];

  float* outb =
      out + (size_t)(b * N_DIM + n0 + wr * 128) * O_DIM + o0 + wc * 64 + lcol;
#pragma unroll
  for (int mi = 0; mi < 8; ++mi) {
#pragma unroll
    for (int r = 0; r < 4; ++r) {
      float* orow = outb + (size_t)(mi * 16 + lq * 4 + r) * O_DIM;
#pragma unroll
      for (int ni = 0; ni < 4; ++ni)
        orow[ni * 16] = acc[mi][ni][r] + bv[ni];
    }
  }
}

extern "C" void kernel_launch(void* const* d_in, const int* in_sizes, int n_in,
                              void* d_out, int out_size, void* d_ws, size_t ws_size,
                              hipStream_t stream) {
  const float* x = (const float*)d_in[0];
  const int* subject_id = (const int*)d_in[1];
  const float* weight = (const float*)d_in[2];
  const float* bias = (const float*)d_in[3];
  float* out = (float*)d_out;

  unsigned short* wb = (unsigned short*)d_ws;  // 16 MiB

  cvt_w<<<2048, 256, 0, stream>>>(weight, wb);

  scl_gemm<<<256, 512, 0, stream>>>(x, subject_id, wb, bias, out);
}